// Round 5
// baseline (219.580 us; speedup 1.0000x reference)
//
#include <hip/hip_runtime.h>

#define N_NODES 16384
#define FIN     256
#define FOUT    64
#define MAXW    128   // nnz/row: mean ~33, sigma ~5.7; 128 is ~16 sigma headroom

typedef float f32x4 __attribute__((ext_vector_type(4)));

// ---------------- Kernel 1: support = x @ weight  [N,FIN]@[FIN,FOUT] ----------
__global__ __launch_bounds__(256) void support_gemm(
    const float* __restrict__ x, const float* __restrict__ w,
    float* __restrict__ support) {
  __shared__ float wl[FIN * FOUT];   // 64 KB  [k][c]
  __shared__ float xl[16][FIN];      // 16 KB  [r][k]
  const int t = threadIdx.x;

  const float4* w4 = (const float4*)w;
  float4* wl4 = (float4*)wl;
#pragma unroll
  for (int i = 0; i < 16; ++i) wl4[i * 256 + t] = w4[i * 256 + t];

  const int row0 = blockIdx.x * 16;
  const float4* x4 = (const float4*)(x + (size_t)row0 * FIN);
  float4* xl4 = (float4*)xl;
#pragma unroll
  for (int i = 0; i < 4; ++i) xl4[i * 256 + t] = x4[i * 256 + t];
  __syncthreads();

  const int wv = t >> 6;
  const int c  = t & 63;
  const int r0 = wv * 4;
  float acc0 = 0.f, acc1 = 0.f, acc2 = 0.f, acc3 = 0.f;

#pragma unroll 4
  for (int k = 0; k < FIN; k += 4) {
    const f32x4 xv0 = *(const f32x4*)&xl[r0 + 0][k];
    const f32x4 xv1 = *(const f32x4*)&xl[r0 + 1][k];
    const f32x4 xv2 = *(const f32x4*)&xl[r0 + 2][k];
    const f32x4 xv3 = *(const f32x4*)&xl[r0 + 3][k];
    const float w0 = wl[(k + 0) * FOUT + c];
    const float w1 = wl[(k + 1) * FOUT + c];
    const float w2 = wl[(k + 2) * FOUT + c];
    const float w3 = wl[(k + 3) * FOUT + c];
    acc0 += xv0[0] * w0 + xv0[1] * w1 + xv0[2] * w2 + xv0[3] * w3;
    acc1 += xv1[0] * w0 + xv1[1] * w1 + xv1[2] * w2 + xv1[3] * w3;
    acc2 += xv2[0] * w0 + xv2[1] * w1 + xv2[2] * w2 + xv2[3] * w3;
    acc3 += xv3[0] * w0 + xv3[1] * w1 + xv3[2] * w2 + xv3[3] * w3;
  }
  float* outp = support + (size_t)(row0 + r0) * FOUT + c;
  outp[0 * FOUT] = acc0;
  outp[1 * FOUT] = acc1;
  outp[2 * FOUT] = acc2;
  outp[3 * FOUT] = acc3;
}

// Ballot-compact the nonzeros of one f32x4 wave-load into the row's list.
// cnt is wave-uniform; no atomics, no LDS.
__device__ __forceinline__ void compact_quad(
    const f32x4 a, const int kbase, int& cnt, int* __restrict__ rowlist) {
#pragma unroll
  for (int e = 0; e < 4; ++e) {
    const unsigned long long mask = __ballot(a[e] != 0.f);
    if (a[e] != 0.f) {
      const int prefix = __builtin_amdgcn_mbcnt_hi(
          (unsigned)(mask >> 32),
          __builtin_amdgcn_mbcnt_lo((unsigned)mask, 0));
      const int slot = cnt + prefix;
      if (slot < MAXW) rowlist[slot] = kbase + e;
    }
    cnt += (int)__popcll(mask);
  }
}

// ---------------- Kernel 2: PURE adj scan -> per-row CSR lists ----------------
// Wave-per-row, no LDS, ballot compaction, 8+8 ping-pong load pipeline so the
// wave always has >=8 stream loads outstanding (no per-batch drain to 0).
__global__ __launch_bounds__(256) void scan_adj(
    const float* __restrict__ adj, int* __restrict__ nbrlist,
    int* __restrict__ nbrcnt) {
  const int t    = threadIdx.x;
  const int wv   = t >> 6;
  const int lane = t & 63;
  const int row  = blockIdx.x * 4 + wv;

  const f32x4* a4 = (const f32x4*)(adj + (size_t)row * N_NODES);
  int* rowlist = nbrlist + (size_t)row * MAXW;
  int cnt = 0;

  f32x4 A[8], B[8];
#pragma unroll
  for (int j = 0; j < 8; ++j)
    A[j] = __builtin_nontemporal_load(&a4[j * 64 + lane]);

#pragma unroll 1
  for (int h = 0; h < 8; h += 2) {
    // issue odd batch while even batch is in flight
    if (h + 1 < 8) {
#pragma unroll
      for (int j = 0; j < 8; ++j)
        B[j] = __builtin_nontemporal_load(&a4[(h + 1) * 512 + j * 64 + lane]);
    }
#pragma unroll
    for (int j = 0; j < 8; ++j)
      compact_quad(A[j], (h * 512 + j * 64 + lane) * 4, cnt, rowlist);

    if (h + 2 < 8) {
#pragma unroll
      for (int j = 0; j < 8; ++j)
        A[j] = __builtin_nontemporal_load(&a4[(h + 2) * 512 + j * 64 + lane]);
    }
    if (h + 1 < 8) {
#pragma unroll
      for (int j = 0; j < 8; ++j)
        compact_quad(B[j], ((h + 1) * 512 + j * 64 + lane) * 4, cnt, rowlist);
    }
  }
  if (lane == 0) nbrcnt[row] = min(cnt, MAXW);
}

// ---------------- Kernel 3: gather + mean + bias ------------------------------
__global__ __launch_bounds__(256) void gather_mean(
    const int* __restrict__ nbrlist, const int* __restrict__ nbrcnt,
    const float* __restrict__ support, const float* __restrict__ bias,
    float* __restrict__ out) {
  const int t    = threadIdx.x;
  const int wv   = t >> 6;
  const int lane = t & 63;
  const int row  = blockIdx.x * 4 + wv;

  const int m = nbrcnt[row];
  const int* rowlist = nbrlist + (size_t)row * MAXW;
  const float* sup = support + lane;

  float s0 = 0.f, s1 = 0.f, s2 = 0.f, s3 = 0.f;
  int   c0 = 0, c1 = 0, c2 = 0, c3 = 0;
  int n = 0;
  for (; n + 4 <= m; n += 4) {
    const float v0 = sup[(size_t)rowlist[n + 0] * FOUT];
    const float v1 = sup[(size_t)rowlist[n + 1] * FOUT];
    const float v2 = sup[(size_t)rowlist[n + 2] * FOUT];
    const float v3 = sup[(size_t)rowlist[n + 3] * FOUT];
    s0 += v0; c0 += (v0 != 0.f);
    s1 += v1; c1 += (v1 != 0.f);
    s2 += v2; c2 += (v2 != 0.f);
    s3 += v3; c3 += (v3 != 0.f);
  }
  for (; n < m; ++n) {
    const float v = sup[(size_t)rowlist[n] * FOUT];
    s0 += v; c0 += (v != 0.f);
  }
  const float s = (s0 + s1) + (s2 + s3);
  const int   c = (c0 + c1) + (c2 + c3);
  out[(size_t)row * FOUT + lane] = s / (float)c + bias[lane];
}

// ---------------- Fallback (R4 fused aggregate) if ws too small ---------------
__global__ __launch_bounds__(256) void aggregate_fused(
    const float* __restrict__ adj, const float* __restrict__ support,
    const float* __restrict__ bias, float* __restrict__ out) {
  __shared__ int nbr[4][512];
  __shared__ int cnt[4];
  const int t = threadIdx.x, wv = t >> 6, lane = t & 63;
  const int row = blockIdx.x * 4 + wv;
  if (lane == 0) cnt[wv] = 0;
  const f32x4* a4 = (const f32x4*)(adj + (size_t)row * N_NODES);
#pragma unroll 1
  for (int h = 0; h < 8; ++h) {
    f32x4 av[8];
#pragma unroll
    for (int j = 0; j < 8; ++j)
      av[j] = __builtin_nontemporal_load(&a4[h * 512 + j * 64 + lane]);
#pragma unroll
    for (int j = 0; j < 8; ++j) {
      const f32x4 a = av[j];
      const int nz = (a[0] != 0.f) + (a[1] != 0.f) + (a[2] != 0.f) + (a[3] != 0.f);
      if (nz) {
        int p = atomicAdd(&cnt[wv], nz);
        if (p + nz <= 512) {
          const int kbase = (h * 512 + j * 64 + lane) * 4;
          if (a[0] != 0.f) nbr[wv][p++] = kbase;
          if (a[1] != 0.f) nbr[wv][p++] = kbase + 1;
          if (a[2] != 0.f) nbr[wv][p++] = kbase + 2;
          if (a[3] != 0.f) nbr[wv][p++] = kbase + 3;
        }
      }
    }
  }
  __syncthreads();
  const int m = min(cnt[wv], 512);
  float s0 = 0.f, s1 = 0.f, s2 = 0.f, s3 = 0.f;
  int   c0 = 0, c1 = 0, c2 = 0, c3 = 0;
  int n = 0;
  const float* sup = support + lane;
  for (; n + 4 <= m; n += 4) {
    const float v0 = sup[(size_t)nbr[wv][n + 0] * FOUT];
    const float v1 = sup[(size_t)nbr[wv][n + 1] * FOUT];
    const float v2 = sup[(size_t)nbr[wv][n + 2] * FOUT];
    const float v3 = sup[(size_t)nbr[wv][n + 3] * FOUT];
    s0 += v0; c0 += (v0 != 0.f);
    s1 += v1; c1 += (v1 != 0.f);
    s2 += v2; c2 += (v2 != 0.f);
    s3 += v3; c3 += (v3 != 0.f);
  }
  for (; n < m; ++n) {
    const float v = sup[(size_t)nbr[wv][n] * FOUT];
    s0 += v; c0 += (v != 0.f);
  }
  const float s = (s0 + s1) + (s2 + s3);
  const int   c = (c0 + c1) + (c2 + c3);
  out[(size_t)row * FOUT + lane] = s / (float)c + bias[lane];
}

extern "C" void kernel_launch(void* const* d_in, const int* in_sizes, int n_in,
                              void* d_out, int out_size, void* d_ws, size_t ws_size,
                              hipStream_t stream) {
  const float* x    = (const float*)d_in[0];
  const float* adj  = (const float*)d_in[1];
  const float* w    = (const float*)d_in[2];
  const float* bias = (const float*)d_in[3];
  float* out = (float*)d_out;

  float* support = (float*)d_ws;                                  // 4 MB
  const size_t sup_bytes  = (size_t)N_NODES * FOUT * 4;
  const size_t list_bytes = (size_t)N_NODES * MAXW * 4;           // 8 MB
  int* nbrlist = (int*)((char*)d_ws + sup_bytes);
  int* nbrcnt  = (int*)((char*)d_ws + sup_bytes + list_bytes);    // 64 KB

  support_gemm<<<N_NODES / 16, 256, 0, stream>>>(x, w, support);

  if (ws_size >= sup_bytes + list_bytes + (size_t)N_NODES * 4) {
    scan_adj<<<N_NODES / 4, 256, 0, stream>>>(adj, nbrlist, nbrcnt);
    gather_mean<<<N_NODES / 4, 256, 0, stream>>>(nbrlist, nbrcnt, support, bias, out);
  } else {
    aggregate_fused<<<N_NODES / 4, 256, 0, stream>>>(adj, support, bias, out);
  }
}